// Round 19
// baseline (37.544 us; speedup 1.0000x reference)
//
#include <hip/hip_runtime.h>

typedef _Float16 f16x8  __attribute__((ext_vector_type(8)));
typedef _Float16 f16x2  __attribute__((ext_vector_type(2)));
typedef float    f32x16 __attribute__((ext_vector_type(16)));
typedef unsigned uint2v __attribute__((ext_vector_type(2)));

// ---- global ws layout (halfword units) ----
// pre [2][170][64] : f16(W1[:,:50]@emb+b1); k=50 -> 1.0 (bias lane); 51..63 = 0
// w1g [2][64]      : W1 glicko column, k>=50 = 0
// w2  [2][32][64]  : W2[m][k] (m<25); k=50 col = b2[m]; row25 k50 = 1.0; else 0
// w3  [2][10][32]  : W3[t][m] (m<25); m=25 col = b3[t]; else 0
// wfr [10][2][16]  : Wf rows per slot, t>=10 = 0
#define GPRE  0
#define GW1G  21760
#define GW2   21888
#define GW3   25984
#define GWFR  26624                  // + 320 -> 26944 hw

// ---- LDS layout (halfword units) ----
// pre [340][56] (overrun reads hit zero-K cols of W2 -> exact, r14-proven)
// w1g [2][64]; w2 [64][72]; w3 [20][40]; wfr [10][40]
#define LPS   56
#define L_PRE 0
#define L_W1  19040
#define L_W2  19168
#define L_W3  23776
#define L_WFR 24576
#define L_END 24976                  // 49952 B -> 3 blocks/CU

__global__ void precompute(const float* __restrict__ emb,
                           const float* __restrict__ W1a, const float* __restrict__ b1a,
                           const float* __restrict__ W2a, const float* __restrict__ b2a,
                           const float* __restrict__ W3a, const float* __restrict__ b3a,
                           const float* __restrict__ W1b, const float* __restrict__ b1b,
                           const float* __restrict__ W2b, const float* __restrict__ b2b,
                           const float* __restrict__ W3b, const float* __restrict__ b3b,
                           const float* __restrict__ Wf,
                           _Float16* __restrict__ ws16)
{
    const int team = blockIdx.y;
    const float* __restrict__ W1 = team ? W1b : W1a;
    const float* __restrict__ B1 = team ? b1b : b1a;
    const float* __restrict__ W2 = team ? W2b : W2a;
    const float* __restrict__ B2 = team ? b2b : b2a;
    const float* __restrict__ W3 = team ? W3b : W3a;
    const float* __restrict__ B3 = team ? b3b : b3a;
    const int tid = threadIdx.x;

    if (blockIdx.x < 170) {
        const int cc = blockIdx.x;
        const int k = tid;
        float v = 0.0f;
        if (k < 50) {
            v = B1[k];
            for (int d = 0; d < 50; ++d)
                v = fmaf(W1[k * 51 + d], emb[cc * 50 + d], v);
        } else if (k == 50) {
            v = 1.0f;                                   // bias lane for layer-2 fold
        }
        ws16[GPRE + team * 170 * 64 + cc * 64 + k] = (_Float16)v;
    } else {
        for (int i = tid; i < 64; i += 64)
            ws16[GW1G + team * 64 + i] = (_Float16)((i < 50) ? W1[i * 51 + 50] : 0.0f);
        for (int i = tid; i < 32 * 64; i += 64) {
            const int m = i >> 6, k = i & 63;
            float v = 0.0f;
            if (m < 25) v = (k < 50) ? W2[m * 50 + k] : (k == 50 ? B2[m] : 0.0f);
            else if (m == 25 && k == 50) v = 1.0f;      // h2[25] = 1 (layer-3 bias lane)
            ws16[GW2 + team * 2048 + i] = (_Float16)v;
        }
        for (int i = tid; i < 10 * 32; i += 64) {
            const int t = i >> 5, m = i & 31;
            float v = 0.0f;
            if (m < 25) v = W3[t * 25 + m];
            else if (m == 25) v = B3[t];
            ws16[GW3 + team * 320 + i] = (_Float16)v;
        }
        for (int i = tid; i < 5 * 2 * 16; i += 64) {    // wfr [slot][row][16]
            const int s = i >> 5, r = (i >> 4) & 1, k = i & 15;
            ws16[GWFR + team * 160 + i] =
                (_Float16)((k < 10) ? Wf[r * 100 + team * 50 + s * 10 + k] : 0.0f);
        }
    }
}

__device__ __forceinline__ f16x8 hfma8(f16x8 a, f16x8 b, f16x8 c) {
    return __builtin_elementwise_fma(a, b, c);
}
__device__ __forceinline__ f16x8 hrelu8(f16x8 a) {
    const f16x8 z = {0, 0, 0, 0, 0, 0, 0, 0};
    return __builtin_elementwise_max(a, z);
}
__device__ __forceinline__ unsigned relupk(float a, float b) {
    f16x2 t = __builtin_bit_cast(f16x2, __builtin_amdgcn_cvt_pkrtz(a, b));
    const f16x2 z = {0, 0};
    t = __builtin_elementwise_max(t, z);
    return __builtin_bit_cast(unsigned, t);
}
__device__ __forceinline__ uint2v plswap(unsigned a, unsigned b) {
    // D[32:63] <-> S[0:31]: r[0] = {a.lo | b.lo-from-partner}, r[1] = {a.hi-from-partner | b.hi}
    return __builtin_amdgcn_permlane32_swap(a, b, false, false);
}
union w4 { unsigned u[4]; f16x8 v; };

// Round-19: 32x32x16 MFMA restructure -- one wave owns 32 samples.
// Layer2 = 4 chained MFMAs (K=64, biases folded into k=50 lane), layer3 = 2
// (b3 folded into m=25 lane via h2[25]=1), final = 1: 7 MFMAs / 32 samples =
// half the per-sample MFMA/DS-fragment/VALU cost of the r12-r18 plateau
// structure, and half the waves. C->B-frag redistribution between layers is
// 4+2 permlane32_swap (T12, in-register, no LDS round-trip). C-ins are
// inline-0 (biases folded) -> no bias registers. LDS ~50 KB -> 3 blocks/CU.
__global__ __launch_bounds__(512)
__attribute__((amdgpu_waves_per_eu(4, 4)))
void match_predict(const float* __restrict__ feat, const _Float16* __restrict__ ws16,
                   const float* __restrict__ bf, float* __restrict__ out, int nB)
{
    __shared__ __align__(16) _Float16 sm16[L_END];

    const int tid = threadIdx.x;
    const int l  = tid & 63;
    const int c  = l & 31;          // sample column (and A-frag row index)
    const int g  = l >> 5;          // k-half group
    const int wv = tid >> 6;

    // ---- stage tables: global ws -> LDS, once per block ----
    for (int i = tid; i < 340 * 7; i += 512) {            // pre: 64 -> 56 stride
        const int r = i / 7, ch = i - r * 7;
        *(f16x8*)(sm16 + L_PRE + r * LPS + ch * 8) =
            *(const f16x8*)(ws16 + GPRE + r * 64 + ch * 8);
    }
    for (int i = tid; i < 16; i += 512)
        *(f16x8*)(sm16 + L_W1 + i * 8) = *(const f16x8*)(ws16 + GW1G + i * 8);
    for (int i = tid; i < 64 * 8; i += 512) {             // w2: 64 -> 72 stride
        const int r = i >> 3, ch = i & 7;
        *(f16x8*)(sm16 + L_W2 + r * 72 + ch * 8) =
            *(const f16x8*)(ws16 + GW2 + r * 64 + ch * 8);
    }
    for (int i = tid; i < 20 * 4; i += 512) {             // w3: 32 -> 40 stride
        const int r = i >> 2, ch = i & 3;
        *(f16x8*)(sm16 + L_W3 + r * 40 + ch * 8) =
            *(const f16x8*)(ws16 + GW3 + r * 32 + ch * 8);
    }
    for (int i = tid; i < 10 * 4; i += 512) {             // wfr: 32 -> 40 stride
        const int r = i >> 2, ch = i & 3;
        *(f16x8*)(sm16 + L_WFR + r * 40 + ch * 8) =
            *(const f16x8*)(ws16 + GWFR + r * 32 + ch * 8);
    }
    __syncthreads();

    const float bf0 = bf[0], bf1 = bf[1];
    const int nchunks = (nB + 255) >> 8;                  // 256 samples / block-chunk
    const f32x16 Z16 = {};

    for (int ck = blockIdx.x; ck < nchunks; ck += gridDim.x) {
        const int base = ck * 256 + wv * 32;
        if (base >= nB) continue;
        const int sample = base + c;
        const int sEff   = (sample < nB) ? sample : (nB - 1);

        const float4* f4 = reinterpret_cast<const float4*>(feat + (size_t)sEff * 12);
        const float4 v0 = f4[0], v1 = f4[1], v2 = f4[2];
        const float fr[12] = {v0.x, v0.y, v0.z, v0.w, v1.x, v1.y, v1.z, v1.w,
                              v2.x, v2.y, v2.z, v2.w};

        f32x16 aout = Z16;                                // final C, chained 10 slots

        #pragma unroll
        for (int team = 0; team < 2; ++team) {
            // A-frags: W2 rows (m = c), 4 K-chunks
            f16x8 w2A[4];
            #pragma unroll
            for (int j = 0; j < 4; ++j)
                w2A[j] = *(const f16x8*)(sm16 + L_W2 + (team * 32 + c) * 72
                                         + j * 16 + g * 8);
            // A-frags: W3 rows (t = c, rows >= 10 are zero via select)
            const bool tv = (c < 10);
            const int  tr = tv ? c : 0;
            f16x8 w3A0 = *(const f16x8*)(sm16 + L_W3 + (team * 10 + tr) * 40 + g * 8);
            f16x8 w3A1 = *(const f16x8*)(sm16 + L_W3 + (team * 10 + tr) * 40 + 16 + g * 8);
            if (!tv) { w3A0 = (f16x8){0,0,0,0,0,0,0,0}; w3A1 = (f16x8){0,0,0,0,0,0,0,0}; }
            // w1g B-side chunks
            f16x8 w1g[4];
            #pragma unroll
            for (int j = 0; j < 4; ++j)
                w1g[j] = *(const f16x8*)(sm16 + L_W1 + team * 64 + j * 16 + g * 8);
            const _Float16 glh = (_Float16)fr[team];
            const f16x8 glv = {glh, glh, glh, glh, glh, glh, glh, glh};

            #pragma unroll
            for (int s5 = 0; s5 < 5; ++s5) {
                const int ci = (int)fr[2 + team * 5 + s5];
                const _Float16* __restrict__ prow =
                    sm16 + L_PRE + (team * 170 + ci) * LPS;

                // h1^T B-frag chunks (k = j*16 + g*8 + i); k=50 lane = 1.0
                f16x8 h1[4];
                #pragma unroll
                for (int j = 0; j < 4; ++j) {
                    const f16x8 p = *(const f16x8*)(prow + j * 16 + g * 8);
                    h1[j] = hrelu8(hfma8(w1g[j], glv, p));
                }

                // layer 2: h2^T[m][c], 4 chained MFMAs, C-in = 0 (bias folded)
                f32x16 acc = __builtin_amdgcn_mfma_f32_32x32x16_f16(w2A[0], h1[0], Z16, 0, 0, 0);
                acc = __builtin_amdgcn_mfma_f32_32x32x16_f16(w2A[1], h1[1], acc, 0, 0, 0);
                acc = __builtin_amdgcn_mfma_f32_32x32x16_f16(w2A[2], h1[2], acc, 0, 0, 0);
                acc = __builtin_amdgcn_mfma_f32_32x32x16_f16(w2A[3], h1[3], acc, 0, 0, 0);

                // relu+pack C pairs: p_i covers rows {g0: 0-3,8-11,16-19,24-27}
                const unsigned p0 = relupk(acc[0],  acc[1]);
                const unsigned p1 = relupk(acc[2],  acc[3]);
                const unsigned p2 = relupk(acc[4],  acc[5]);
                const unsigned p3 = relupk(acc[6],  acc[7]);
                const unsigned p4 = relupk(acc[8],  acc[9]);
                const unsigned p5 = relupk(acc[10], acc[11]);
                const unsigned p6 = relupk(acc[12], acc[13]);
                const unsigned p7 = relupk(acc[14], acc[15]);

                // redistribute -> layer-3 B-frags (k=m), 4 permlane32_swap
                const uint2v s02 = plswap(p0, p2);
                const uint2v s13 = plswap(p1, p3);
                const uint2v s46 = plswap(p4, p6);
                const uint2v s57 = plswap(p5, p7);
                w4 b3c0, b3c1;
                b3c0.u[0] = s02[0]; b3c0.u[1] = s13[0];
                b3c0.u[2] = s02[1]; b3c0.u[3] = s13[1];
                b3c1.u[0] = s46[0]; b3c1.u[1] = s57[0];
                b3c1.u[2] = s46[1]; b3c1.u[3] = s57[1];

                // layer 3: h3^T[t][c], 2 chained MFMAs, C-in = 0 (b3 folded)
                f32x16 a3 = __builtin_amdgcn_mfma_f32_32x32x16_f16(w3A0, b3c0.v, Z16, 0, 0, 0);
                a3 = __builtin_amdgcn_mfma_f32_32x32x16_f16(w3A1, b3c1.v, a3, 0, 0, 0);

                // h3 pack: q0=(t0,1 | t4,5), q1=(t2,3 | t6,7), q2=(t8,9 | 0)
                const unsigned q0 = relupk(a3[0], a3[1]);
                const unsigned q1 = relupk(a3[2], a3[3]);
                const unsigned q2 = relupk(a3[4], a3[5]);
                const uint2v sAq = plswap(q0, q2);
                const uint2v sBq = plswap(q1, 0u);
                w4 bf4;
                bf4.u[0] = sAq[0]; bf4.u[1] = sBq[0];
                bf4.u[2] = sAq[1]; bf4.u[3] = sBq[1];

                // final: A = Wf rows (rows >= 2 zero), C chains across slots
                const bool wvld = (c < 2);
                const int  wrow = c & 1;
                f16x8 wfa = *(const f16x8*)(sm16 + L_WFR + (team * 5 + s5) * 40
                                            + wrow * 16 + g * 8);
                if (!wvld) wfa = (f16x8){0,0,0,0,0,0,0,0};
                aout = __builtin_amdgcn_mfma_f32_32x32x16_f16(wfa, bf4.v, aout, 0, 0, 0);
            }
        }

        // aout: col = c, row0/row1 (regs 0,1 of lanes g=0) = out0/out1
        if (g == 0 && sample < nB) {
            reinterpret_cast<float2*>(out)[sample] =
                make_float2(aout[0] + bf0, aout[1] + bf1);
        }
    }
}

extern "C" void kernel_launch(void* const* d_in, const int* in_sizes, int n_in,
                              void* d_out, int out_size, void* d_ws, size_t ws_size,
                              hipStream_t stream) {
    const float* feat = (const float*)d_in[0];
    const float* emb  = (const float*)d_in[1];
    const float* W1a  = (const float*)d_in[2];
    const float* b1a  = (const float*)d_in[3];
    const float* W2a  = (const float*)d_in[4];
    const float* b2a  = (const float*)d_in[5];
    const float* W3a  = (const float*)d_in[6];
    const float* b3a  = (const float*)d_in[7];
    const float* W1b  = (const float*)d_in[8];
    const float* b1b  = (const float*)d_in[9];
    const float* W2b  = (const float*)d_in[10];
    const float* b2b  = (const float*)d_in[11];
    const float* W3b  = (const float*)d_in[12];
    const float* b3b  = (const float*)d_in[13];
    const float* Wf   = (const float*)d_in[14];
    const float* bf   = (const float*)d_in[15];
    float* out = (float*)d_out;
    _Float16* ws16 = (_Float16*)d_ws;

    const int nB = in_sizes[0] / 12;

    precompute<<<dim3(171, 2), 64, 0, stream>>>(emb,
        W1a, b1a, W2a, b2a, W3a, b3a,
        W1b, b1b, W2b, b2b, W3b, b3b, Wf, ws16);

    const int nchunks = (nB + 255) / 256;
    int blocks = 768;                               // 3 blocks/CU, co-resident
    if (blocks > nchunks) blocks = nchunks;
    match_predict<<<blocks, 512, 0, stream>>>(feat, ws16, bf, out, nB);
}

// Round 20
// 35.743 us; speedup vs baseline: 1.0504x; 1.0504x over previous
//
#include <hip/hip_runtime.h>

typedef _Float16 f16x8 __attribute__((ext_vector_type(8)));
typedef _Float16 f16x4 __attribute__((ext_vector_type(4)));
typedef _Float16 f16x2 __attribute__((ext_vector_type(2)));
typedef float    f32x4 __attribute__((ext_vector_type(4)));

// ---- global ws layout (halfword units), produced by precompute ----
#define PRE_OFF   0
#define PRE_SZ    (2 * 170 * 64)
#define W1G_OFF   (PRE_OFF + PRE_SZ)          // 21760 (128 hw)
#define W2P_OFF   (W1G_OFF + 2 * 64)          // 21888 (4096 hw)
#define W3P_OFF   (W2P_OFF + 2 * 32 * 64)     // 25984 (1024 hw)
#define WFR_OFF   (W3P_OFF + 2 * 16 * 32)     // 27008 (320 hw)
#define H16_END   (WFR_OFF + 320)             // 27328
#define FOFF      H16_END
#define B2P_F     0
#define B3P_F     (B2P_F + 2 * 32)            // 64  (+32) -> 96 floats

// ---- LDS layout (halfword units) ----
// pre [340][56], w2 [64][72], w3 [32][40], w1g [2][64], wfr [10][40], smf[96]f
// Total 51.3 KB -> 3 blocks/CU (r16/r18-validated).
#define LP_STR  56
#define L_PRE   0
#define L_W1    (340 * LP_STR)                // 19040
#define L_W2    (L_W1 + 128)                  // 19168
#define L_W3    (L_W2 + 64 * 72)              // 23776
#define L_WFR   (L_W3 + 32 * 40)              // 25056
#define L_END   (L_WFR + 10 * 40)             // 25456 hw = 50912 B

__global__ void precompute(const float* __restrict__ emb,
                           const float* __restrict__ W1a, const float* __restrict__ b1a,
                           const float* __restrict__ W2a, const float* __restrict__ b2a,
                           const float* __restrict__ W3a, const float* __restrict__ b3a,
                           const float* __restrict__ W1b, const float* __restrict__ b1b,
                           const float* __restrict__ W2b, const float* __restrict__ b2b,
                           const float* __restrict__ W3b, const float* __restrict__ b3b,
                           const float* __restrict__ Wf,
                           _Float16* __restrict__ ws16)
{
    const int team = blockIdx.y;
    const float* __restrict__ W1 = team ? W1b : W1a;
    const float* __restrict__ B1 = team ? b1b : b1a;
    const float* __restrict__ W2 = team ? W2b : W2a;
    const float* __restrict__ B2 = team ? b2b : b2a;
    const float* __restrict__ W3 = team ? W3b : W3a;
    const float* __restrict__ B3 = team ? b3b : b3a;
    float* __restrict__ wsf = (float*)(ws16 + FOFF);
    const int tid = threadIdx.x;

    if (blockIdx.x < 170) {
        const int cc = blockIdx.x;
        const int k = tid;
        float v = 0.0f;
        if (k < 50) {
            v = B1[k];
            for (int d = 0; d < 50; ++d)
                v = fmaf(W1[k * 51 + d], emb[cc * 50 + d], v);
        }
        ws16[PRE_OFF + team * 170 * 64 + cc * 64 + k] = (_Float16)v;
    } else {
        for (int i = tid; i < 64; i += 64)
            ws16[W1G_OFF + team * 64 + i] = (_Float16)((i < 50) ? W1[i * 51 + 50] : 0.0f);
        for (int i = tid; i < 32 * 64; i += 64) {
            const int m = i >> 6, k = i & 63;
            ws16[W2P_OFF + team * 2048 + i] =
                (_Float16)((m < 25 && k < 50) ? W2[m * 50 + k] : 0.0f);
        }
        for (int i = tid; i < 16 * 32; i += 64) {
            const int t = i >> 5, m = i & 31;
            ws16[W3P_OFF + team * 512 + i] =
                (_Float16)((t < 10 && m < 25) ? W3[t * 25 + m] : 0.0f);
        }
        for (int i = tid; i < 5 * 2 * 16; i += 64) {
            const int s = i >> 5, r = (i >> 4) & 1, k = i & 15;
            ws16[WFR_OFF + team * 160 + i] =
                (_Float16)((k < 10) ? Wf[r * 100 + team * 50 + s * 10 + k] : 0.0f);
        }
        for (int i = tid; i < 32; i += 64) wsf[B2P_F + team * 32 + i] = (i < 25) ? B2[i] : 0.0f;
        for (int i = tid; i < 16; i += 64) wsf[B3P_F + team * 16 + i] = (i < 10) ? B3[i] : 0.0f;
    }
}

__device__ __forceinline__ f16x8 hfma8(f16x8 a, f16x8 b, f16x8 c) {
    return __builtin_elementwise_fma(a, b, c);
}
__device__ __forceinline__ f16x8 hrelu8(f16x8 a) {
    const f16x8 z = {0, 0, 0, 0, 0, 0, 0, 0};
    return __builtin_elementwise_max(a, z);
}
__device__ __forceinline__ f16x4 hrelu4(f16x4 a) {
    const f16x4 z = {0, 0, 0, 0};
    return __builtin_elementwise_max(a, z);
}
__device__ __forceinline__ f16x2 pkrtz(float a, float b) {
    return __builtin_bit_cast(f16x2, __builtin_amdgcn_cvt_pkrtz(a, b));
}

// Round-20 = round-18 body with the team loop OUTSIDE the chunk loop.
// r18's ledger: 48 DS reads/wave-chunk x 64 wave-chunks/CU x 12cy ~= 15us of
// per-CU LDS-pipe busy, and 28 of the 48 are chunk-invariant weight-fragment
// reloads. Team-outer hoists all fragments to ONCE per wave: DS/CU ~7us.
// Team-1 pass accumulates into out[] via same-thread read-modify-write
// (chunk ownership fixed by blockIdx -> no cross-thread race; same thread
// wrote the team-0 partial). One team's fragments (~50 VGPR) live at a time
// -> fits the (4,4) 128-VGPR no-spill budget. LDS/grid/chain-split kept.
__global__ __launch_bounds__(512)
__attribute__((amdgpu_waves_per_eu(4, 4)))
void match_predict(const float* __restrict__ feat, const _Float16* __restrict__ ws16,
                   const float* __restrict__ bf, float* __restrict__ out, int nB)
{
    __shared__ __align__(16) _Float16 sm16[L_END];
    __shared__ __align__(16) float    smf[96];

    const int tid = threadIdx.x;
    const int l  = tid & 63;
    const int c  = l & 15;          // sample column
    const int g  = l >> 4;          // k-chunk / row group
    const int wv = tid >> 6;

    // ---- stage tables: global ws -> LDS, once per block ----
    for (int i = tid; i < 340 * 7; i += 512) {            // pre: 64 -> 56 stride
        const int r = i / 7, ch = i - r * 7;
        *(f16x8*)(sm16 + L_PRE + r * LP_STR + ch * 8) =
            *(const f16x8*)(ws16 + PRE_OFF + r * 64 + ch * 8);
    }
    for (int i = tid; i < 16; i += 512)
        *(f16x8*)(sm16 + L_W1 + i * 8) = *(const f16x8*)(ws16 + W1G_OFF + i * 8);
    for (int i = tid; i < 64 * 8; i += 512) {             // w2: 64 -> 72 stride
        const int r = i >> 3, ch = i & 7;
        *(f16x8*)(sm16 + L_W2 + r * 72 + ch * 8) =
            *(const f16x8*)(ws16 + W2P_OFF + r * 64 + ch * 8);
    }
    for (int i = tid; i < 32 * 4; i += 512) {             // w3: 32 -> 40 stride
        const int r = i >> 2, ch = i & 3;
        *(f16x8*)(sm16 + L_W3 + r * 40 + ch * 8) =
            *(const f16x8*)(ws16 + W3P_OFF + r * 32 + ch * 8);
    }
    for (int i = tid; i < 40; i += 512) {                 // wfr: 32 -> 40 stride
        const int ts = i >> 2, ch = i & 3;
        *(f16x8*)(sm16 + L_WFR + ts * 40 + ch * 8) =
            *(const f16x8*)(ws16 + WFR_OFF + ts * 32 + ch * 8);
    }
    for (int i = tid; i < 24; i += 512)
        *(f32x4*)(smf + i * 4) = *(const f32x4*)((const float*)(ws16 + FOFF) + i * 4);
    __syncthreads();

    const float bf0 = bf[0], bf1 = bf[1];
    const int nchunks = (nB + 127) >> 7;
    const f32x4 zero4 = {0.f, 0.f, 0.f, 0.f};

    #pragma unroll
    for (int team = 0; team < 2; ++team) {
        // ---- this team's fragments: loaded ONCE per wave (was: every chunk) ----
        f16x8 w2A[2][2];
        #pragma unroll
        for (int mt = 0; mt < 2; ++mt)
            #pragma unroll
            for (int kf = 0; kf < 2; ++kf)
                w2A[mt][kf] = *(const f16x8*)(sm16 + L_W2
                                 + (team * 32 + mt * 16 + c) * 72 + kf * 32 + g * 8);
        const f16x4 w3A0 = *(const f16x4*)(sm16 + L_W3 + (team * 16 + c) * 40 + 4 * g);
        const f16x4 w3A1 = *(const f16x4*)(sm16 + L_W3 + (team * 16 + c) * 40 + 16 + 4 * g);
        const f16x8 w1gA = *(const f16x8*)(sm16 + L_W1 + team * 64 + g * 8);
        const f16x8 w1gB = *(const f16x8*)(sm16 + L_W1 + team * 64 + 32 + g * 8);
        f16x4 wfrA[5];
        #pragma unroll
        for (int s = 0; s < 5; ++s)
            wfrA[s] = *(const f16x4*)(sm16 + L_WFR + (team * 5 + s) * 40
                                      + (c & 1) * 16 + 4 * g);
        const f32x4 b2lo = *(const f32x4*)(smf + B2P_F + team * 32 + 4 * g);
        const f32x4 b2hi = *(const f32x4*)(smf + B2P_F + team * 32 + 16 + 4 * g);
        const f32x4 b3v  = *(const f32x4*)(smf + B3P_F + team * 16 + 4 * g);

        for (int ck = blockIdx.x; ck < nchunks; ck += gridDim.x) {
            const int base = ck * 128 + wv * 16;
            if (base >= nB) continue;
            const int sample = base + c;
            const int sEff   = (sample < nB) ? sample : (nB - 1);

            const float4* f4 = reinterpret_cast<const float4*>(feat + (size_t)sEff * 12);
            const float4 v0 = f4[0], v1 = f4[1], v2 = f4[2];
            const float fr[12] = {v0.x, v0.y, v0.z, v0.w, v1.x, v1.y, v1.z, v1.w,
                                  v2.x, v2.y, v2.z, v2.w};
            const _Float16 glh = (_Float16)fr[team];
            const f16x8 glv = {glh, glh, glh, glh, glh, glh, glh, glh};

            f32x4 aoutE = zero4, aoutO = zero4;

            // prime the pre-row pipeline with this team's slot 0
            f16x8 pc0, pc1;
            {
                const int ci0 = (int)fr[2 + team * 5];
                const _Float16* p = sm16 + L_PRE + (team * 170 + ci0) * LP_STR;
                pc0 = *(const f16x8*)(p + g * 8);
                pc1 = *(const f16x8*)(p + 32 + g * 8);
            }

            #pragma unroll
            for (int s5 = 0; s5 < 5; ++s5) {
                // issue next slot's pre-row reads before this slot's compute
                f16x8 pn0 = pc0, pn1 = pc1;
                if (s5 < 4) {
                    const int cin = (int)fr[3 + team * 5 + s5];
                    const _Float16* pn = sm16 + L_PRE + (team * 170 + cin) * LP_STR;
                    pn0 = *(const f16x8*)(pn + g * 8);
                    pn1 = *(const f16x8*)(pn + 32 + g * 8);
                }

                // h1^T B-frag
                const f16x8 h10 = hrelu8(hfma8(w1gA, glv, pc0));
                const f16x8 h11 = hrelu8(hfma8(w1gB, glv, pc1));

                // layer 2: two INDEPENDENT MFMAs per tile, one add
                f32x4 a0  = __builtin_amdgcn_mfma_f32_16x16x32_f16(w2A[0][0], h10, b2lo,  0, 0, 0);
                f32x4 a0x = __builtin_amdgcn_mfma_f32_16x16x32_f16(w2A[0][1], h11, zero4, 0, 0, 0);
                f32x4 a1  = __builtin_amdgcn_mfma_f32_16x16x32_f16(w2A[1][0], h10, b2hi,  0, 0, 0);
                f32x4 a1x = __builtin_amdgcn_mfma_f32_16x16x32_f16(w2A[1][1], h11, zero4, 0, 0, 0);
                a0 = a0 + a0x;
                a1 = a1 + a1x;

                // pack (RTZ) then relu in f16 domain
                const f16x2 p00 = pkrtz(a0[0], a0[1]);
                const f16x2 p01 = pkrtz(a0[2], a0[3]);
                const f16x2 p10 = pkrtz(a1[0], a1[1]);
                const f16x2 p11 = pkrtz(a1[2], a1[3]);
                const f16x4 b3t0 = hrelu4((f16x4){p00.x, p00.y, p01.x, p01.y});
                const f16x4 b3t1 = hrelu4((f16x4){p10.x, p10.y, p11.x, p11.y});

                // layer 3: two independent MFMAs, one add
                f32x4 a3  = __builtin_amdgcn_mfma_f32_16x16x16f16(w3A0, b3t0, b3v,   0, 0, 0);
                f32x4 a3x = __builtin_amdgcn_mfma_f32_16x16x16f16(w3A1, b3t1, zero4, 0, 0, 0);
                a3 = a3 + a3x;

                // final layer MFMA into parity-split accumulator
                const f16x2 q0 = pkrtz(a3[0], a3[1]);
                const f16x2 q1 = pkrtz(a3[2], a3[3]);
                const f16x4 h3f = hrelu4((f16x4){q0.x, q0.y, q1.x, q1.y});
                if (s5 & 1)
                    aoutO = __builtin_amdgcn_mfma_f32_16x16x16f16(wfrA[s5], h3f, aoutO, 0, 0, 0);
                else
                    aoutE = __builtin_amdgcn_mfma_f32_16x16x16f16(wfrA[s5], h3f, aoutE, 0, 0, 0);

                pc0 = pn0; pc1 = pn1;
            }

            const f32x4 aout = aoutE + aoutO;
            if (g == 0 && sample < nB) {
                float2* op = reinterpret_cast<float2*>(out) + sample;
                if (team == 0) {
                    *op = make_float2(aout[0] + bf0, aout[1] + bf1);
                } else {
                    const float2 p = *op;        // written by this same thread in pass 0
                    *op = make_float2(p.x + aout[0], p.y + aout[1]);
                }
            }
        }
    }
}

extern "C" void kernel_launch(void* const* d_in, const int* in_sizes, int n_in,
                              void* d_out, int out_size, void* d_ws, size_t ws_size,
                              hipStream_t stream) {
    const float* feat = (const float*)d_in[0];
    const float* emb  = (const float*)d_in[1];
    const float* W1a  = (const float*)d_in[2];
    const float* b1a  = (const float*)d_in[3];
    const float* W2a  = (const float*)d_in[4];
    const float* b2a  = (const float*)d_in[5];
    const float* W3a  = (const float*)d_in[6];
    const float* b3a  = (const float*)d_in[7];
    const float* W1b  = (const float*)d_in[8];
    const float* b1b  = (const float*)d_in[9];
    const float* W2b  = (const float*)d_in[10];
    const float* b2b  = (const float*)d_in[11];
    const float* W3b  = (const float*)d_in[12];
    const float* b3b  = (const float*)d_in[13];
    const float* Wf   = (const float*)d_in[14];
    const float* bf   = (const float*)d_in[15];
    float* out = (float*)d_out;
    _Float16* ws16 = (_Float16*)d_ws;

    const int nB = in_sizes[0] / 12;

    precompute<<<dim3(171, 2), 64, 0, stream>>>(emb,
        W1a, b1a, W2a, b2a, W3a, b3a,
        W1b, b1b, W2b, b2b, W3b, b3b, Wf, ws16);

    const int nchunks = (nB + 127) / 128;
    int blocks = 768;                               // 3 blocks/CU, all co-resident
    if (blocks > nchunks) blocks = nchunks;
    match_predict<<<blocks, 512, 0, stream>>>(feat, ws16, bf, out, nB);
}